// Round 9
// baseline (26.576 us; speedup 1.0000x reference)
//
#include <hip/hip_runtime.h>

// Problem constants (match reference)
#define BB 64
#define HH 480
#define WW 640
#define PP 8192
#define CHUNKS 16          // blocks per batch; PP/CHUNKS = 512 = TPB*2 -> 2 pairs/thread
#define TPB 256
#define GRID (BB * CHUNKS) // 1024 blocks -> 4 blocks/CU -> 16 waves/CU

// Native clang vector type (accepted by __builtin_nontemporal_load)
typedef int v2i __attribute__((ext_vector_type(2)));

// Fused single-kernel design:
//  - Blocks publish partials with atomicExch (RMW -> device-coherent point,
//    NO cache fences / NO L2 invalidates -- the R2 failure mode).
//  - Last-block election: monotone counter, fetch_add, compare mod GRID.
//    Works for ANY initial counter value (0xAA poison, leftover from prior
//    replays) -- no memset node, no reliance on buffer state.
//  - Last block re-reads all partials via atomicAdd(p, 0.0f) (RMW reads at
//    the same coherent point; immune to stale clean L2 lines).
//  - Final reduction replicates the R8 rdl_final order exactly -> bitwise
//    deterministic output.
// ws layout (floats): [0 .. GRID*4) partials {s_log,s_sq,n_log,n_sq} per block
//                     [GRID*4]      uint arrival counter (monotone)

__global__ __launch_bounds__(TPB) void rdl_fused(
    const float* __restrict__ depth,   // [B, H*W]
    const int*  __restrict__ xA,
    const int*  __restrict__ yA,
    const int*  __restrict__ xB,
    const int*  __restrict__ yB,
    const int*  __restrict__ rel,
    float*        __restrict__ ws,
    unsigned int* __restrict__ counter,
    float*        __restrict__ out)
{
    const int bid = blockIdx.x;
    const int b   = bid & (BB - 1);    // batch (pins batch -> XCD: bid%8 == b%8)
    const int c   = bid >> 6;          // chunk 0..15
    const int tid = threadIdx.x;
    const int pair0 = b * PP + c * (PP / CHUNKS) + tid * 2;

    // Coalesced, nontemporal vector index loads (streaming, no reuse)
    const v2i xa2 = __builtin_nontemporal_load(reinterpret_cast<const v2i*>(xA  + pair0));
    const v2i ya2 = __builtin_nontemporal_load(reinterpret_cast<const v2i*>(yA  + pair0));
    const v2i xb2 = __builtin_nontemporal_load(reinterpret_cast<const v2i*>(xB  + pair0));
    const v2i yb2 = __builtin_nontemporal_load(reinterpret_cast<const v2i*>(yB  + pair0));
    const v2i rr2 = __builtin_nontemporal_load(reinterpret_cast<const v2i*>(rel + pair0));

    const int xas[2] = {xa2.x, xa2.y};
    const int yas[2] = {ya2.x, ya2.y};
    const int xbs[2] = {xb2.x, xb2.y};
    const int ybs[2] = {yb2.x, yb2.y};
    const int rs [2] = {rr2.x, rr2.y};

    const float* __restrict__ img = depth + (size_t)b * (HH * WW);

    // Gathers: invalid pairs (r==2, 25%) redirect to img[0] (hot line)
    float zA[2], zB[2];
#pragma unroll
    for (int k = 0; k < 2; ++k) {
        const bool valid = (rs[k] != 2);
        const int iA = valid ? (xas[k] * WW + yas[k]) : 0;
        const int iB = valid ? (xbs[k] * WW + ybs[k]) : 0;
        zA[k] = img[iA];
        zB[k] = img[iB];
    }

    float s_log = 0.f, s_sq = 0.f;
    int   n_log = 0,   n_sq = 0;
#pragma unroll
    for (int k = 0; k < 2; ++k) {
        const float pred = zA[k] - zB[k];
        const int r = rs[k];
        if (r != 2) {
            if (r == 0) {
                s_sq += pred * pred;
                n_sq++;
            } else {
                const float x = -(float)r * pred;
                // stable softplus: max(x,0) + log1p(exp(-|x|))
                s_log += fmaxf(x, 0.f) + log1pf(expf(-fabsf(x)));
                n_log++;
            }
        }
    }

    // 64-lane wave reduction
#pragma unroll
    for (int off = 32; off > 0; off >>= 1) {
        s_log += __shfl_down(s_log, off);
        s_sq  += __shfl_down(s_sq,  off);
        n_log += __shfl_down(n_log, off);
        n_sq  += __shfl_down(n_sq,  off);
    }

    __shared__ float4 lds[TPB / 64];
    const int wave = tid >> 6;
    if ((tid & 63) == 0)
        lds[wave] = make_float4(s_log, s_sq, (float)n_log, (float)n_sq);
    __syncthreads();

    __shared__ int lastFlag;
    if (tid == 0) {
        float4 acc = lds[0];
#pragma unroll
        for (int wv = 1; wv < TPB / 64; ++wv) {
            acc.x += lds[wv].x;
            acc.y += lds[wv].y;
            acc.z += lds[wv].z;
            acc.w += lds[wv].w;
        }
        // Publish partial via RMW (device-coherent point, no fences)
        const float o0 = atomicExch(&ws[bid * 4 + 0], acc.x);
        const float o1 = atomicExch(&ws[bid * 4 + 1], acc.y);
        const float o2 = atomicExch(&ws[bid * 4 + 2], acc.z);
        const float o3 = atomicExch(&ws[bid * 4 + 3], acc.w);
        // Consume returns -> vmcnt drains before counter RMW issues;
        // "memory" clobber stops compiler reordering the counter atomic up.
        asm volatile("" :: "v"(o0), "v"(o1), "v"(o2), "v"(o3) : "memory");
        const unsigned int old = atomicAdd(counter, 1u);
        lastFlag = ((old & (GRID - 1)) == (GRID - 1));
    }
    __syncthreads();
    if (!lastFlag) return;

    // ---- last-arriving block: final reduction (same order as R8's rdl_final)
    const int batch = tid >> 2;        // 0..63
    const int sub   = tid & 3;         // 4 threads per batch
    float sl = 0.f, ss = 0.f, nl = 0.f, ns = 0.f;
#pragma unroll
    for (int k = 0; k < CHUNKS / 4; ++k) {
        const int chunk = sub * (CHUNKS / 4) + k;
        const int base  = (chunk * BB + batch) * 4;   // partial idx = c*64 + b
        sl += atomicAdd(&ws[base + 0], 0.0f);  // RMW read at coherent point
        ss += atomicAdd(&ws[base + 1], 0.0f);
        nl += atomicAdd(&ws[base + 2], 0.0f);
        ns += atomicAdd(&ws[base + 3], 0.0f);
    }
    // combine the 4 sub-threads of each batch (contiguous lanes, same wave)
#pragma unroll
    for (int off = 1; off < 4; off <<= 1) {
        sl += __shfl_xor(sl, off);
        ss += __shfl_xor(ss, off);
        nl += __shfl_xor(nl, off);
        ns += __shfl_xor(ns, off);
    }
    __shared__ float lossArr[BB];
    if (sub == 0)
        lossArr[batch] = sl / nl + ss / ns;   // per-batch log_loss + sq_loss
    __syncthreads();
    if (tid < BB) {                    // wave 0
        float loss = lossArr[tid];
#pragma unroll
        for (int off = 32; off > 0; off >>= 1)
            loss += __shfl_down(loss, off);
        if (tid == 0)
            out[0] = loss * (1.0f / (float)BB);
    }
}

extern "C" void kernel_launch(void* const* d_in, const int* in_sizes, int n_in,
                              void* d_out, int out_size, void* d_ws, size_t ws_size,
                              hipStream_t stream) {
    const float* depth = (const float*)d_in[0];
    const int*   xA    = (const int*)d_in[1];
    const int*   yA    = (const int*)d_in[2];
    const int*   xB    = (const int*)d_in[3];
    const int*   yB    = (const int*)d_in[4];
    const int*   rel   = (const int*)d_in[5];
    float*       out   = (float*)d_out;
    float*       ws    = (float*)d_ws;                       // GRID*4 floats + counter
    unsigned int* counter = (unsigned int*)(ws + GRID * 4);  // monotone, any init OK

    rdl_fused<<<GRID, TPB, 0, stream>>>(depth, xA, yA, xB, yB, rel, ws, counter, out);
}

// Round 10
// 18.691 us; speedup vs baseline: 1.4219x; 1.4219x over previous
//
#include <hip/hip_runtime.h>

// Problem constants (match reference)
#define BB 64
#define HH 480
#define WW 640
#define PP 8192
#define CHUNKS 16          // blocks per batch; PP/CHUNKS = 512 = TPB*2 -> 2 pairs/thread
#define TPB 256
#define GRID (BB * CHUNKS) // 1024 blocks -> 4 blocks/CU -> 16 waves/CU

// Native clang vector type (accepted by __builtin_nontemporal_load)
typedef int v2i __attribute__((ext_vector_type(2)));

// Block mapping: b = bid & 63, c = bid >> 6.
// XCD(bid) = bid % 8 = b % 8 -> all 16 chunk-blocks of batch b land on ONE XCD
// (no cross-XCD duplicate line fetches; ~1.5 touches/line reuse captured).
// Invalid pairs (r==2, 25% of all pairs) redirect their gather address to
// img[0] (one always-hot line) -> ~25% fewer random HBM line fetches, with
// straight-line code (v_cndmask on address, no divergence).
// Fusion REJECTED twice: R2 (agent-scope fences -> per-block L2 invalidates,
// 5x loss) and R9 (atomic publish/election tail serializes ~8 us, + election
// needs a counter reset). Two kernels is the stable optimum.

__global__ __launch_bounds__(TPB) void rdl_partial(
    const float* __restrict__ depth,   // [B, H*W]
    const int*  __restrict__ xA,
    const int*  __restrict__ yA,
    const int*  __restrict__ xB,
    const int*  __restrict__ yB,
    const int*  __restrict__ rel,
    float4*     __restrict__ ws)       // [GRID] partials {s_log, s_sq, n_log, n_sq}
{
    const int bid = blockIdx.x;
    const int b   = bid & (BB - 1);    // batch (pins batch -> XCD)
    const int c   = bid >> 6;          // chunk 0..15
    const int tid = threadIdx.x;
    const int pair0 = b * PP + c * (PP / CHUNKS) + tid * 2;

    // Coalesced, nontemporal vector index loads (streaming, no reuse)
    const v2i xa2 = __builtin_nontemporal_load(reinterpret_cast<const v2i*>(xA  + pair0));
    const v2i ya2 = __builtin_nontemporal_load(reinterpret_cast<const v2i*>(yA  + pair0));
    const v2i xb2 = __builtin_nontemporal_load(reinterpret_cast<const v2i*>(xB  + pair0));
    const v2i yb2 = __builtin_nontemporal_load(reinterpret_cast<const v2i*>(yB  + pair0));
    const v2i rr2 = __builtin_nontemporal_load(reinterpret_cast<const v2i*>(rel + pair0));

    const int xas[2] = {xa2.x, xa2.y};
    const int yas[2] = {ya2.x, ya2.y};
    const int xbs[2] = {xb2.x, xb2.y};
    const int ybs[2] = {yb2.x, yb2.y};
    const int rs [2] = {rr2.x, rr2.y};

    const float* __restrict__ img = depth + (size_t)b * (HH * WW);

    // Gathers: invalid pairs (r==2) load img[0] instead (hot line, no HBM fetch)
    float zA[2], zB[2];
#pragma unroll
    for (int k = 0; k < 2; ++k) {
        const bool valid = (rs[k] != 2);
        const int iA = valid ? (xas[k] * WW + yas[k]) : 0;
        const int iB = valid ? (xbs[k] * WW + ybs[k]) : 0;
        zA[k] = img[iA];
        zB[k] = img[iB];
    }

    float s_log = 0.f, s_sq = 0.f;
    int   n_log = 0,   n_sq = 0;
#pragma unroll
    for (int k = 0; k < 2; ++k) {
        const float pred = zA[k] - zB[k];
        const int r = rs[k];
        if (r != 2) {
            if (r == 0) {
                s_sq += pred * pred;
                n_sq++;
            } else {
                const float x = -(float)r * pred;
                // stable softplus: max(x,0) + log1p(exp(-|x|))
                s_log += fmaxf(x, 0.f) + log1pf(expf(-fabsf(x)));
                n_log++;
            }
        }
    }

    // 64-lane wave reduction
#pragma unroll
    for (int off = 32; off > 0; off >>= 1) {
        s_log += __shfl_down(s_log, off);
        s_sq  += __shfl_down(s_sq,  off);
        n_log += __shfl_down(n_log, off);
        n_sq  += __shfl_down(n_sq,  off);
    }

    __shared__ float4 lds[TPB / 64];
    const int wave = tid >> 6;
    if ((tid & 63) == 0)
        lds[wave] = make_float4(s_log, s_sq, (float)n_log, (float)n_sq);
    __syncthreads();

    if (tid == 0) {
        float4 acc = lds[0];
#pragma unroll
        for (int wv = 1; wv < TPB / 64; ++wv) {
            acc.x += lds[wv].x;
            acc.y += lds[wv].y;
            acc.z += lds[wv].z;
            acc.w += lds[wv].w;
        }
        ws[bid] = acc;   // index = c*64 + b
    }
}

__global__ __launch_bounds__(TPB) void rdl_final(
    const float4* __restrict__ ws,     // [GRID] partials, index = c*64 + b
    float*        __restrict__ out)
{
    const int tid   = threadIdx.x;     // 256 threads
    const int batch = tid >> 2;        // 0..63
    const int sub   = tid & 3;         // 4 threads per batch
    float sl = 0.f, ss = 0.f, nl = 0.f, ns = 0.f;
#pragma unroll
    for (int k = 0; k < CHUNKS / 4; ++k) {
        const int chunk = sub * (CHUNKS / 4) + k;
        const float4 v = ws[chunk * BB + batch];
        sl += v.x; ss += v.y; nl += v.z; ns += v.w;
    }
    // combine the 4 sub-threads of each batch (contiguous lanes, same wave)
#pragma unroll
    for (int off = 1; off < 4; off <<= 1) {
        sl += __shfl_xor(sl, off);
        ss += __shfl_xor(ss, off);
        nl += __shfl_xor(nl, off);
        ns += __shfl_xor(ns, off);
    }
    __shared__ float lossArr[BB];
    if (sub == 0)
        lossArr[batch] = sl / nl + ss / ns;   // per-batch log_loss + sq_loss
    __syncthreads();
    if (tid < BB) {                    // wave 0
        float loss = lossArr[tid];
#pragma unroll
        for (int off = 32; off > 0; off >>= 1)
            loss += __shfl_down(loss, off);
        if (tid == 0)
            out[0] = loss * (1.0f / (float)BB);
    }
}

extern "C" void kernel_launch(void* const* d_in, const int* in_sizes, int n_in,
                              void* d_out, int out_size, void* d_ws, size_t ws_size,
                              hipStream_t stream) {
    const float* depth = (const float*)d_in[0];
    const int*   xA    = (const int*)d_in[1];
    const int*   yA    = (const int*)d_in[2];
    const int*   xB    = (const int*)d_in[3];
    const int*   yB    = (const int*)d_in[4];
    const int*   rel   = (const int*)d_in[5];
    float*       out   = (float*)d_out;
    float4*      ws    = (float4*)d_ws;   // GRID*16 B = 16 KiB

    rdl_partial<<<GRID, TPB, 0, stream>>>(depth, xA, yA, xB, yB, rel, ws);
    rdl_final<<<1, TPB, 0, stream>>>(ws, out);
}